// Round 14
// baseline (799.606 us; speedup 1.0000x reference)
//
#include <hip/hip_runtime.h>
#include <cstdint>
#include <cstddef>

#define XLD 161   // x row stride = NFEAT + EXTRA + 1
#define GA  2048  // agg grid: 8 blocks/CU x 256 CU

typedef float f4u __attribute__((ext_vector_type(4), aligned(4)));  // unaligned-tolerant
typedef float f4a __attribute__((ext_vector_type(4)));              // 16B-aligned
typedef float f3u __attribute__((ext_vector_type(3), aligned(4)));
typedef float f2a __attribute__((ext_vector_type(2)));              // 8B-aligned

// ============================ CSR build ============================
__global__ void hist_kernel(const int* __restrict__ row, int* __restrict__ cnt, int E) {
    for (int e = blockIdx.x * blockDim.x + threadIdx.x; e < E; e += gridDim.x * blockDim.x)
        atomicAdd(&cnt[row[e]], 1);
}

__global__ __launch_bounds__(256)
void scan1_kernel(const int* __restrict__ cnt, int* __restrict__ offs,
                  int* __restrict__ bsums, int n) {
    int t = threadIdx.x;
    int gid = blockIdx.x * 256 + t;
    int v = (gid < n) ? cnt[gid] : 0;
    int x = v;
#pragma unroll
    for (int o = 1; o < 64; o <<= 1) { int y = __shfl_up(x, o); if ((t & 63) >= o) x += y; }
    __shared__ int ws[4];
    if ((t & 63) == 63) ws[t >> 6] = x;
    __syncthreads();
    int add = 0;
    for (int w = 0; w < (t >> 6); w++) add += ws[w];
    int incl = x + add;
    if (gid < n) offs[gid] = incl - v;
    if (t == 255) bsums[blockIdx.x] = incl;
}

__global__ __launch_bounds__(256)
void scan2_kernel(int* __restrict__ bsums, int nb) {
    int t = threadIdx.x;
    int v = (t < nb) ? bsums[t] : 0;
    int x = v;
#pragma unroll
    for (int o = 1; o < 64; o <<= 1) { int y = __shfl_up(x, o); if ((t & 63) >= o) x += y; }
    __shared__ int ws[4];
    if ((t & 63) == 63) ws[t >> 6] = x;
    __syncthreads();
    int add = 0;
    for (int w = 0; w < (t >> 6); w++) add += ws[w];
    if (t < nb) bsums[t] = x + add - v;
}

__global__ void scan3_kernel(int* __restrict__ offs, int* __restrict__ cursor,
                             const int* __restrict__ bsums, int n, int E) {
    int gid = blockIdx.x * 256 + threadIdx.x;
    if (gid < n) {
        int o = offs[gid] + bsums[blockIdx.x];
        offs[gid] = o;
        cursor[gid] = o;
    }
    if (gid == 0) offs[n] = E;
}

__global__ void scatter_kernel(const int* __restrict__ row, const int* __restrict__ col,
                               const float* __restrict__ val, int* __restrict__ cursor,
                               int2* __restrict__ cvA, int E) {
    for (int e = blockIdx.x * blockDim.x + threadIdx.x; e < E; e += gridDim.x * blockDim.x) {
        int r = row[e];
        int p = atomicAdd(&cursor[r], 1);
        cvA[p] = make_int2(col[e], __float_as_int(val[e]));
    }
}

// ============================ Pure aggregation ============================
template <int LC, bool WVS>   // LC floats per lane; row width = 32*LC
__global__ __launch_bounds__(256)
void aggP(const float* __restrict__ S, int ldS, const int* __restrict__ offs,
          const int2* __restrict__ cvA,
          float* __restrict__ Aout, float* __restrict__ vout, int n) {
    int lane = threadIdx.x & 63;
    int lg   = lane & 31;
    int grp  = threadIdx.x >> 5;
    int sh   = lane & 32;

    for (int node = blockIdx.x * 8 + grp; node < n; node += gridDim.x * 8) {
        int e0 = offs[node], e1 = offs[node + 1];
        float acc[LC];
#pragma unroll
        for (int a = 0; a < LC; a++) acc[a] = 0.f;
        float vsum = 0.f;

        for (int e = e0; e < e1; e += 32) {
            int   idx = e + lg;
            int2  cv = (idx < e1) ? cvA[idx] : make_int2(0, 0);
            int   ce = cv.x;
            float ve = __int_as_float(cv.y);
            int   cnt = min(32, e1 - e);
#pragma unroll 8
            for (int j = 0; j < cnt; j++) {
                int   c = __shfl(ce, sh + j);
                float v = __shfl(ve, sh + j);
                const float* srow = S + (size_t)c * ldS + LC * lg;
                if (LC == 3) {
                    f3u g = *(const f3u*)srow;
                    acc[0] = fmaf(v, g[0], acc[0]);
                    acc[1] = fmaf(v, g[1], acc[1]);
                    acc[2] = fmaf(v, g[2], acc[2]);
                } else {
                    f4u g = *(const f4u*)srow;
                    acc[0] = fmaf(v, g[0], acc[0]);
                    acc[1] = fmaf(v, g[1], acc[1]);
                    acc[2] = fmaf(v, g[2], acc[2]);
                    acc[3] = fmaf(v, g[3], acc[3]);
                }
                vsum += v;
            }
        }

        float* orow = Aout + (size_t)node * (32 * LC) + LC * lg;
        if (LC == 3) {
            f3u o; o[0] = acc[0]; o[1] = acc[1]; o[2] = acc[2];
            *(f3u*)orow = o;
        } else {
            f4u o; o[0] = acc[0]; o[1] = acc[1]; o[2] = acc[2]; o[3] = acc[3];
            *(f4u*)orow = o;
        }
        if (WVS && lg == 0) vout[node] = vsum;
    }
}

// ===== aggB: gather 96-wide + bias + relu + BN partials + vsum (layer-1 tail) =====
__global__ __launch_bounds__(256)
void aggB(const float* __restrict__ S, const int* __restrict__ offs,
          const int2* __restrict__ cvA, const float* __restrict__ bias,
          float* __restrict__ Hout, float* __restrict__ vout,
          float* __restrict__ pbuf, int n) {
    __shared__ float sS[96], sQ[96];
    int t = threadIdx.x;
    if (t < 96) { sS[t] = 0.f; sQ[t] = 0.f; }
    __syncthreads();
    int lane = t & 63, lg = lane & 31, grp = t >> 5, sh = lane & 32;
    float bb[3];
    bb[0] = bias[3 * lg]; bb[1] = bias[3 * lg + 1]; bb[2] = bias[3 * lg + 2];
    float ps[3] = {0.f, 0.f, 0.f}, pq[3] = {0.f, 0.f, 0.f};

    for (int node = blockIdx.x * 8 + grp; node < n; node += gridDim.x * 8) {
        int e0 = offs[node], e1 = offs[node + 1];
        float acc[3] = {0.f, 0.f, 0.f};
        float vsum = 0.f;
        for (int e = e0; e < e1; e += 32) {
            int   idx = e + lg;
            int2  cv = (idx < e1) ? cvA[idx] : make_int2(0, 0);
            int   ce = cv.x;
            float ve = __int_as_float(cv.y);
            int   cnt = min(32, e1 - e);
#pragma unroll 8
            for (int j = 0; j < cnt; j++) {
                int   c = __shfl(ce, sh + j);
                float v = __shfl(ve, sh + j);
                const float* srow = S + (size_t)c * 96 + 3 * lg;
                f3u g = *(const f3u*)srow;
                acc[0] = fmaf(v, g[0], acc[0]);
                acc[1] = fmaf(v, g[1], acc[1]);
                acc[2] = fmaf(v, g[2], acc[2]);
                vsum += v;
            }
        }
        float* orow = Hout + (size_t)node * 96 + 3 * lg;
        f3u o;
#pragma unroll
        for (int a = 0; a < 3; a++) {
            float v = fmaxf(acc[a] + bb[a], 0.f);
            o[a] = v;
            ps[a] += v; pq[a] += v * v;
        }
        *(f3u*)orow = o;
        if (lg == 0) vout[node] = vsum;
    }
#pragma unroll
    for (int a = 0; a < 3; a++) {
        atomicAdd(&sS[3 * lg + a], ps[a]);
        atomicAdd(&sQ[3 * lg + a], pq[a]);
    }
    __syncthreads();
    if (t < 96) {
        pbuf[(size_t)blockIdx.x * 192 + t]      = sS[t];
        pbuf[(size_t)blockIdx.x * 192 + 96 + t] = sQ[t];
    }
}

// reduce pbuf[nb][192] -> stats[192]
__global__ __launch_bounds__(256)
void bn_reduce(const float* __restrict__ pbuf, float* __restrict__ stats, int nb) {
    int t = threadIdx.x;
    if (t < 192) {
        float s = 0.f;
        for (int pb = blockIdx.x; pb < nb; pb += gridDim.x)
            s += pbuf[(size_t)pb * 192 + t];
        atomicAdd(&stats[t], s);
    }
}

// ===== aggC: gather 64-wide + relu(acc + vsum*cb + bias) (layer-5 tail) =====
__global__ __launch_bounds__(256)
void aggC(const float* __restrict__ S, const int* __restrict__ offs,
          const int2* __restrict__ cvA, const float* __restrict__ bias,
          const float* __restrict__ cb, const float* __restrict__ vsum,
          float* __restrict__ Hout, int n) {
    int lane = threadIdx.x & 63, lg = lane & 31, grp = threadIdx.x >> 5, sh = lane & 32;
    float bb0 = bias[2 * lg], bb1 = bias[2 * lg + 1];
    float cc0 = cb[2 * lg],   cc1 = cb[2 * lg + 1];

    for (int node = blockIdx.x * 8 + grp; node < n; node += gridDim.x * 8) {
        int e0 = offs[node], e1 = offs[node + 1];
        float a0 = 0.f, a1 = 0.f;
        for (int e = e0; e < e1; e += 32) {
            int   idx = e + lg;
            int2  cv = (idx < e1) ? cvA[idx] : make_int2(0, 0);
            int   ce = cv.x;
            float ve = __int_as_float(cv.y);
            int   cnt = min(32, e1 - e);
#pragma unroll 8
            for (int j = 0; j < cnt; j++) {
                int   c = __shfl(ce, sh + j);
                float v = __shfl(ve, sh + j);
                f2a g = *(const f2a*)(S + (size_t)c * 64 + 2 * lg);
                a0 = fmaf(v, g[0], a0);
                a1 = fmaf(v, g[1], a1);
            }
        }
        float vs = vsum[node];
        f2a o;
        o[0] = fmaxf(a0 + vs * cc0 + bb0, 0.f);
        o[1] = fmaxf(a1 + vs * cc1 + bb1, 0.f);
        *(f2a*)(Hout + (size_t)node * 64 + 2 * lg) = o;
    }
}

// ============================ Tiled GEMM v3: 32-row tile, K-chunk 32 ============================
// 1563 blocks (vs 782) -> ~6 blocks/CU resident; 3 barrier-pairs for K=96 (vs 6).
template <int CT>
__device__ inline void ldw(const float* p, float* wv) {
    if constexpr (CT == 4) { *(f4a*)wv = *(const f4a*)p; }
    else if constexpr (CT == 6) { *(f3u*)wv = *(const f3u*)p; *(f3u*)(wv + 3) = *(const f3u*)(p + 3); }
    else { *(f4a*)wv = *(const f4a*)p; *(f4a*)(wv + 4) = *(const f4a*)(p + 4); }
}

// DOT mode (C=64 only): m[r] = sum_c relu(acc[r][c]+bias[c]) * cbv[c] + vsum[0];
template <int K, int C, bool DOBN, bool HASCB, bool LIN = false, bool DOT = false>
__global__ __launch_bounds__(256)
void gemmF(const float* __restrict__ A1, int ld1, int split,
           const float* __restrict__ A2, int ld2,
           const float* __restrict__ W, const float* __restrict__ bias,
           const float* __restrict__ cbv, const float* __restrict__ vsum,
           float* __restrict__ Out, float* __restrict__ bsum,
           float* __restrict__ bsumsq, int n) {
    constexpr int CT = C / 16;           // 4, 6, or 8
    __shared__ float Wc[32 * C];         // current 32-k chunk of W
    __shared__ float At[32][34];         // [k][row], pad 34
    __shared__ float redS[DOBN ? C : 1];
    __shared__ float redQ[DOBN ? C : 1];

    int t  = threadIdx.x;
    int tc = t & 15, tr = t >> 4;
    int row0 = blockIdx.x * 32;

    if (DOBN && t < C) { redS[t] = 0.f; redQ[t] = 0.f; }

    // staging role: thread stages row srow, 4 k's at kh (32 rows x 8 k-groups)
    int srow = t >> 3;
    int gr = row0 + srow; if (gr >= n) gr = n - 1;
    int kh = (t & 7) * 4;

    float acc[2][CT];
#pragma unroll
    for (int i = 0; i < 2; i++)
#pragma unroll
        for (int c = 0; c < CT; c++) acc[i][c] = 0.f;

    for (int kb = 0; kb < K; kb += 32) {
        __syncthreads();
        for (int i = t * 4; i < 32 * C; i += 1024)
            *(f4a*)&Wc[i] = *(const f4u*)&W[(size_t)kb * C + i];
        {
            int kg = kb + kh;
            const float* src = (kg < split) ? (A1 + (size_t)gr * ld1 + kg)
                                            : (A2 + (size_t)gr * ld2 + (kg - split));
            f4u v = *(const f4u*)src;
#pragma unroll
            for (int e = 0; e < 4; e++) At[kh + e][srow] = v[e];
        }
        __syncthreads();
#pragma unroll
        for (int kk = 0; kk < 32; kk++) {
            f2a av = *(const f2a*)&At[kk][tr * 2];
            float wv[CT];
            ldw<CT>(&Wc[kk * C + tc * CT], wv);
#pragma unroll
            for (int i = 0; i < 2; i++)
#pragma unroll
                for (int c = 0; c < CT; c++) acc[i][c] = fmaf(av[i], wv[c], acc[i][c]);
        }
    }

    if constexpr (DOT) {
        // bias = M2b, cbv = M3w (64), vsum = M3b (1), Out = m, bsum = (float*)gmin
        float bb2[CT], ww[CT];
#pragma unroll
        for (int c = 0; c < CT; c++) { bb2[c] = bias[tc * CT + c]; ww[c] = cbv[tc * CT + c]; }
        float b3 = vsum[0];
        float lmin = 3.4e38f;
#pragma unroll
        for (int i = 0; i < 2; i++) {
            float d = 0.f;
#pragma unroll
            for (int c = 0; c < CT; c++) d = fmaf(fmaxf(acc[i][c] + bb2[c], 0.f), ww[c], d);
            d += __shfl_xor(d, 1); d += __shfl_xor(d, 2);
            d += __shfl_xor(d, 4); d += __shfl_xor(d, 8);
            int r = row0 + tr * 2 + i;
            if (tc == 0 && r < n) {
                float mv = d + b3;
                Out[r] = mv;
                lmin = fminf(lmin, mv);
            }
        }
        __shared__ float smin[16];
        if (tc == 0) smin[tr] = lmin;
        __syncthreads();
        if (t == 0) {
            float mn = smin[0];
#pragma unroll
            for (int i2 = 1; i2 < 16; i2++) mn = fminf(mn, smin[i2]);
            unsigned u = __float_as_uint(mn);
            unsigned key = (u >> 31) ? ~u : (u | 0x80000000u);
            atomicMin((unsigned*)bsum, key);
        }
        return;
    }

    float bb[CT], cc[CT];
#pragma unroll
    for (int c = 0; c < CT; c++) {
        bb[c] = LIN ? 0.f : bias[tc * CT + c];
        cc[c] = HASCB ? cbv[tc * CT + c] : 0.f;
    }
    float ps[CT], pq[CT];
#pragma unroll
    for (int c = 0; c < CT; c++) { ps[c] = 0.f; pq[c] = 0.f; }

#pragma unroll
    for (int i = 0; i < 2; i++) {
        int r = row0 + tr * 2 + i;
        if (r < n) {
            float vs = HASCB ? vsum[r] : 0.f;
            float* o = Out + (size_t)r * C + tc * CT;
#pragma unroll
            for (int c = 0; c < CT; c++) {
                float v = acc[i][c] + vs * cc[c] + bb[c];
                if (!LIN) v = fmaxf(v, 0.f);
                o[c] = v;
                if (DOBN) { ps[c] += v; pq[c] += v * v; }
            }
        }
    }
    if (DOBN) {
#pragma unroll
        for (int c = 0; c < CT; c++) {
            ps[c] += __shfl_xor(ps[c], 16);
            ps[c] += __shfl_xor(ps[c], 32);
            pq[c] += __shfl_xor(pq[c], 16);
            pq[c] += __shfl_xor(pq[c], 32);
        }
        if ((t & 48) == 0) {   // one lane per tc per wave
#pragma unroll
            for (int c = 0; c < CT; c++) {
                atomicAdd(&redS[tc * CT + c], ps[c]);
                atomicAdd(&redQ[tc * CT + c], pq[c]);
            }
        }
        __syncthreads();
        if (t < C) {
            atomicAdd(&bsum[t], redS[t]);
            atomicAdd(&bsumsq[t], redQ[t]);
        }
    }
}

// ============================ BN fold ============================
// Wf[k*C + j] = inv[k] * W[k][j]  (k-major)
template <int C>
__global__ __launch_bounds__(256)
void fold_kernel(const float* __restrict__ W, float* __restrict__ bsum,
                 float* __restrict__ bsumsq, float* __restrict__ Wf,
                 float* __restrict__ cb, int N) {
    __shared__ float mean[96], inv[96];
    int t = threadIdx.x;
    float rn = 1.0f / (float)N;
    if (t < 96) {
        float mu  = bsum[t] * rn;
        float var = bsumsq[t] * rn - mu * mu;
        mean[t] = mu;
        inv[t]  = rsqrtf(var + 1e-5f);
        bsum[t] = 0.f;
        bsumsq[t] = 0.f;
    }
    __syncthreads();
    for (int i = t; i < 96 * C; i += 256) {
        int k = i / C;
        Wf[i] = inv[k] * W[i];
    }
    if (t < C) {
        float s = 0.f;
        for (int k = 0; k < 96; k++) s += mean[k] * inv[k] * W[k * C + t];
        cb[t] = -s;
    }
}

// ============================ exact select: two-level LDS radix ============================
__device__ inline unsigned fkey(float f) {
    unsigned u = __float_as_uint(f);
    return (u >> 31) ? ~u : (u | 0x80000000u);
}

__global__ __launch_bounds__(256)
void where_hist(const float* __restrict__ x, float* __restrict__ m,
                const unsigned* __restrict__ gmin, unsigned* __restrict__ h0, int n) {
    __shared__ unsigned lh[256];
    int t = threadIdx.x;
    lh[t] = 0u;
    __syncthreads();
    unsigned k = *gmin;
    unsigned u = (k >> 31) ? (k ^ 0x80000000u) : ~k;
    float g = __uint_as_float(u);
    for (int i = blockIdx.x * 256 + t; i < n; i += gridDim.x * 256) {
        float mv = m[i];
        if (x[(size_t)i * XLD + 160] == 0.0f) { mv = g; m[i] = mv; }
        atomicAdd(&lh[fkey(mv) >> 24], 1u);
    }
    __syncthreads();
    if (lh[t]) atomicAdd(&h0[t], lh[t]);
}

__global__ __launch_bounds__(256)
void sel_pick8(const unsigned* __restrict__ h, const unsigned* __restrict__ kres,
               int kconst, unsigned* __restrict__ outb, unsigned* __restrict__ outk) {
    int t = threadIdx.x;
    int bin = 255 - t;
    unsigned k = kres ? *kres : (unsigned)kconst;
    unsigned c = h[bin];
    unsigned x = c;
#pragma unroll
    for (int o = 1; o < 64; o <<= 1) { unsigned y = __shfl_up(x, o); if ((t & 63) >= o) x += y; }
    __shared__ unsigned ws[4];
    if ((t & 63) == 63) ws[t >> 6] = x;
    __syncthreads();
    unsigned add = 0;
    for (int w = 0; w < (t >> 6); w++) add += ws[w];
    unsigned incl = x + add, excl = incl - c;
    if (excl < k && k <= incl) { *outb = (unsigned)bin; *outk = k - excl; }
}

__global__ __launch_bounds__(256)
void sel_hist8b(const float* __restrict__ m, const unsigned* __restrict__ pick,
                unsigned* __restrict__ h1, int n) {
    __shared__ unsigned lh[256];
    int t = threadIdx.x;
    lh[t] = 0u;
    __syncthreads();
    unsigned b0 = pick[0];
    for (int i = blockIdx.x * 256 + t; i < n; i += gridDim.x * 256) {
        unsigned key = fkey(m[i]);
        if ((key >> 24) == b0) atomicAdd(&lh[(key >> 16) & 255u], 1u);
    }
    __syncthreads();
    if (lh[t]) atomicAdd(&h1[t], lh[t]);
}

__global__ void sel_collect(const float* __restrict__ m, const unsigned* __restrict__ pick,
                            unsigned* __restrict__ sbuf, unsigned* __restrict__ scnt, int n) {
    unsigned pfx = (pick[0] << 8) | pick[2];
    for (int i = blockIdx.x * blockDim.x + threadIdx.x; i < n; i += gridDim.x * blockDim.x) {
        unsigned key = fkey(m[i]);
        if ((key >> 16) == pfx) sbuf[atomicAdd(scnt, 1u)] = key;
    }
}

__global__ __launch_bounds__(1024)
void sel_final(const unsigned* __restrict__ sbuf, const unsigned* __restrict__ scnt,
               const unsigned* __restrict__ pick, float* __restrict__ thresh) {
    __shared__ unsigned hist[256];
    __shared__ unsigned spfx;
    __shared__ int skk;
    int t = threadIdx.x;
    int ns = (int)*scnt;
    if (t == 0) { spfx = ((pick[0] << 8) | pick[2]) << 16; skk = (int)pick[3]; }
    __syncthreads();
    for (int pass = 0; pass < 2; ++pass) {
        if (t < 256) hist[t] = 0u;
        __syncthreads();
        int shift = 8 - 8 * pass;
        unsigned pfxmask = (pass == 0) ? 0xFFFF0000u : 0xFFFFFF00u;
        unsigned pfx = spfx;
        for (int i = t; i < ns; i += 1024) {
            unsigned key = sbuf[i];
            if ((key & pfxmask) == pfx) atomicAdd(&hist[(key >> shift) & 255u], 1u);
        }
        __syncthreads();
        if (t == 0) {
            int cum = 0, kk = skk, chosen = 0;
            for (int b = 255; b >= 0; b--) {
                cum += (int)hist[b];
                if (cum >= kk) { chosen = b; kk -= (cum - (int)hist[b]); break; }
            }
            spfx = pfx | ((unsigned)chosen << shift);
            skk = kk;
        }
        __syncthreads();
    }
    if (t == 0) {
        unsigned key = spfx;
        unsigned u = (key >> 31) ? (key ^ 0x80000000u) : ~key;
        *thresh = __uint_as_float(u);
    }
}

__global__ void mask_kernel(const float* __restrict__ m, const float* __restrict__ thresh,
                            float* __restrict__ out, int n) {
    int i = blockIdx.x * blockDim.x + threadIdx.x;
    if (i < n) {
        float t = *thresh, v = m[i];
        out[i] = (v > t) ? v * (1.0f / v) : 0.0f;
    }
}

// ============================ launch ============================
extern "C" void kernel_launch(void* const* d_in, const int* in_sizes, int n_in,
                              void* d_out, int out_size, void* d_ws, size_t ws_size,
                              hipStream_t stream) {
    const float* x   = (const float*)d_in[0];
    const int*   row = (const int*)d_in[1];
    const int*   col = (const int*)d_in[2];
    const float* val = (const float*)d_in[3];
    const float* W1  = (const float*)d_in[4];
    const float* b1  = (const float*)d_in[5];
    const float* W2  = (const float*)d_in[6];
    const float* b2  = (const float*)d_in[7];
    const float* W3  = (const float*)d_in[8];
    const float* b3  = (const float*)d_in[9];
    const float* W4  = (const float*)d_in[10];
    const float* b4  = (const float*)d_in[11];
    const float* W5  = (const float*)d_in[12];
    const float* b5  = (const float*)d_in[13];
    const float* M1w = (const float*)d_in[14];
    const float* M1b = (const float*)d_in[15];
    const float* M2w = (const float*)d_in[16];
    const float* M2b = (const float*)d_in[17];
    const float* M3w = (const float*)d_in[18];
    const float* M3b = (const float*)d_in[19];

    const int n = in_sizes[0] / XLD;   // 50000
    const int E = in_sizes[1];         // 800000

    char* ws = (char*)d_ws;
    size_t off = 0;
    auto carve = [&](size_t bytes) -> void* {
        void* p = ws + off;
        off = (off + bytes + 255) & ~(size_t)255;
        return p;
    };
    int*      offs   = (int*)carve((size_t)(n + 1) * 4);
    int*      cursor = (int*)carve((size_t)n * 4);
    int*      bsums  = (int*)carve(256 * 4);
    int2*     cvA    = (int2*)carve((size_t)E * 8);
    float*    hA     = (float*)carve((size_t)n * 128 * 4);   // buffer A
    float*    hB     = (float*)carve((size_t)n * 128 * 4);   // buffer B
    float*    Wf     = (float*)carve(96 * 96 * 4);
    float*    stats  = (float*)carve(192 * 4);
    float*    cb     = (float*)carve(96 * 4);
    float*    vsum   = (float*)carve((size_t)n * 4);
    float*    m      = (float*)carve((size_t)n * 4);
    unsigned* gmin   = (unsigned*)carve(4);
    float*    thresh = (float*)carve(4);
    unsigned* h0     = (unsigned*)carve(256 * 4);
    unsigned* h1     = (unsigned*)carve(256 * 4);
    unsigned* sbuf   = (unsigned*)carve((size_t)n * 4);
    unsigned* scnt   = (unsigned*)carve(4);
    unsigned* pick   = (unsigned*)carve(16);
    float*    pbuf   = (float*)carve((size_t)GA * 192 * 4);
    float* bsum   = stats;
    float* bsumsq = stats + 96;

    hipMemsetAsync(cursor, 0, (size_t)n * 4, stream);
    hipMemsetAsync(stats, 0, 192 * 4, stream);
    hipMemsetAsync(gmin, 0xFF, 4, stream);
    hipMemsetAsync(h0, 0, 256 * 4, stream);
    hipMemsetAsync(h1, 0, 256 * 4, stream);
    hipMemsetAsync(scnt, 0, 4, stream);

    // CSR build
    const int nb = (n + 255) / 256;
    hist_kernel<<<2048, 256, 0, stream>>>(row, cursor, E);
    scan1_kernel<<<nb, 256, 0, stream>>>(cursor, offs, bsums, n);
    scan2_kernel<<<1, 256, 0, stream>>>(bsums, nb);
    scan3_kernel<<<nb, 256, 0, stream>>>(offs, cursor, bsums, n, E);
    scatter_kernel<<<2048, 256, 0, stream>>>(row, col, val, cursor, cvA, E);

    const int gB = (n + 31) / 32;       // gemmF row tiles (1563)

    // Layer 1 (multiply-first): s1 = x[:,:128] @ W1 (linear) -> hB; h1 = relu(agg(s1)+b1) -> hA
    gemmF<128, 96, false, false, true><<<gB, 256, 0, stream>>>(x, XLD, 128, x, XLD,
        W1, b1, nullptr, nullptr, hB, bsum, bsumsq, n);
    aggB<<<GA, 256, 0, stream>>>(hB, offs, cvA, b1, hA, vsum, pbuf, n);
    bn_reduce<<<64, 256, 0, stream>>>(pbuf, stats, GA);

    // Layers 2-4: split gather + GEMM, ping-pong
    fold_kernel<96><<<1, 256, 0, stream>>>(W2, bsum, bsumsq, Wf, cb, n);
    aggP<3, false><<<GA, 256, 0, stream>>>(hA, 96, offs, cvA, hB, nullptr, n);
    gemmF<96, 96, true, true><<<gB, 256, 0, stream>>>(hB, 96, 96, hB, 96,
        Wf, b2, cb, vsum, hA, bsum, bsumsq, n);

    fold_kernel<96><<<1, 256, 0, stream>>>(W3, bsum, bsumsq, Wf, cb, n);
    aggP<3, false><<<GA, 256, 0, stream>>>(hA, 96, offs, cvA, hB, nullptr, n);
    gemmF<96, 96, true, true><<<gB, 256, 0, stream>>>(hB, 96, 96, hB, 96,
        Wf, b3, cb, vsum, hA, bsum, bsumsq, n);

    fold_kernel<96><<<1, 256, 0, stream>>>(W4, bsum, bsumsq, Wf, cb, n);
    aggP<3, false><<<GA, 256, 0, stream>>>(hA, 96, offs, cvA, hB, nullptr, n);
    gemmF<96, 96, true, true><<<gB, 256, 0, stream>>>(hB, 96, 96, hB, 96,
        Wf, b4, cb, vsum, hA, bsum, bsumsq, n);

    // Layer 5 (multiply-first): s5 = h4 @ W5f (linear, n x 64) -> hB; h5 = relu(agg(s5)+vsum*cb+b5) -> hA
    fold_kernel<64><<<1, 256, 0, stream>>>(W5, bsum, bsumsq, Wf, cb, n);
    gemmF<96, 64, false, false, true><<<gB, 256, 0, stream>>>(hA, 96, 96, hA, 96,
        Wf, b5, nullptr, nullptr, hB, bsum, bsumsq, n);
    aggC<<<GA, 256, 0, stream>>>(hB, offs, cvA, b5, cb, vsum, hA, n);

    // MLP
    gemmF<96, 128, false, false><<<gB, 256, 0, stream>>>(hA, 64, 64, x + 128, XLD,
        M1w, M1b, nullptr, nullptr, hB, bsum, bsumsq, n);
    gemmF<128, 64, false, false, false, true><<<gB, 256, 0, stream>>>(hB, 128, 128, hB, 128,
        M2w, M2b, M3w, M3b, m, (float*)gmin, nullptr, n);

    // where(grp==0, min, m) fused with level-0 select histogram
    where_hist<<<64, 256, 0, stream>>>(x, m, gmin, h0, n);

    // exact 71st-largest threshold (two-level LDS radix)
    sel_pick8<<<1, 256, 0, stream>>>(h0, nullptr, 71, &pick[0], &pick[1]);
    sel_hist8b<<<64, 256, 0, stream>>>(m, pick, h1, n);
    sel_pick8<<<1, 256, 0, stream>>>(h1, &pick[1], 0, &pick[2], &pick[3]);
    sel_collect<<<64, 256, 0, stream>>>(m, pick, sbuf, scnt, n);
    sel_final<<<1, 1024, 0, stream>>>(sbuf, scnt, pick, thresh);

    // out = m>thresh ? m*(1/m) : 0
    mask_kernel<<<(n + 255) / 256, 256, 0, stream>>>(m, thresh, (float*)d_out, n);
}

// Round 15
// 724.975 us; speedup vs baseline: 1.1029x; 1.1029x over previous
//
#include <hip/hip_runtime.h>
#include <cstdint>
#include <cstddef>

#define XLD 161   // x row stride = NFEAT + EXTRA + 1
#define GA  2048  // agg grid: 8 blocks/CU x 256 CU

typedef float f4u __attribute__((ext_vector_type(4), aligned(4)));  // unaligned-tolerant
typedef float f4a __attribute__((ext_vector_type(4)));              // 16B-aligned
typedef float f3u __attribute__((ext_vector_type(3), aligned(4)));
typedef float f2a __attribute__((ext_vector_type(2)));              // 8B-aligned

// ============================ CSR build ============================
__global__ void hist_kernel(const int* __restrict__ row, int* __restrict__ cnt, int E) {
    for (int e = blockIdx.x * blockDim.x + threadIdx.x; e < E; e += gridDim.x * blockDim.x)
        atomicAdd(&cnt[row[e]], 1);
}

__global__ __launch_bounds__(256)
void scan1_kernel(const int* __restrict__ cnt, int* __restrict__ offs,
                  int* __restrict__ bsums, int n) {
    int t = threadIdx.x;
    int gid = blockIdx.x * 256 + t;
    int v = (gid < n) ? cnt[gid] : 0;
    int x = v;
#pragma unroll
    for (int o = 1; o < 64; o <<= 1) { int y = __shfl_up(x, o); if ((t & 63) >= o) x += y; }
    __shared__ int ws[4];
    if ((t & 63) == 63) ws[t >> 6] = x;
    __syncthreads();
    int add = 0;
    for (int w = 0; w < (t >> 6); w++) add += ws[w];
    int incl = x + add;
    if (gid < n) offs[gid] = incl - v;
    if (t == 255) bsums[blockIdx.x] = incl;
}

__global__ __launch_bounds__(256)
void scan2_kernel(int* __restrict__ bsums, int nb) {
    int t = threadIdx.x;
    int v = (t < nb) ? bsums[t] : 0;
    int x = v;
#pragma unroll
    for (int o = 1; o < 64; o <<= 1) { int y = __shfl_up(x, o); if ((t & 63) >= o) x += y; }
    __shared__ int ws[4];
    if ((t & 63) == 63) ws[t >> 6] = x;
    __syncthreads();
    int add = 0;
    for (int w = 0; w < (t >> 6); w++) add += ws[w];
    if (t < nb) bsums[t] = x + add - v;
}

__global__ void scan3_kernel(int* __restrict__ offs, int* __restrict__ cursor,
                             const int* __restrict__ bsums, int n, int E) {
    int gid = blockIdx.x * 256 + threadIdx.x;
    if (gid < n) {
        int o = offs[gid] + bsums[blockIdx.x];
        offs[gid] = o;
        cursor[gid] = o;
    }
    if (gid == 0) offs[n] = E;
}

__global__ void scatter_kernel(const int* __restrict__ row, const int* __restrict__ col,
                               const float* __restrict__ val, int* __restrict__ cursor,
                               int2* __restrict__ cvA, int E) {
    for (int e = blockIdx.x * blockDim.x + threadIdx.x; e < E; e += gridDim.x * blockDim.x) {
        int r = row[e];
        int p = atomicAdd(&cursor[r], 1);
        cvA[p] = make_int2(col[e], __float_as_int(val[e]));
    }
}

// ============================ Pure aggregation ============================
template <int LC, bool WVS>   // LC floats per lane; row width = 32*LC
__global__ __launch_bounds__(256)
void aggP(const float* __restrict__ S, int ldS, const int* __restrict__ offs,
          const int2* __restrict__ cvA,
          float* __restrict__ Aout, float* __restrict__ vout, int n) {
    int lane = threadIdx.x & 63;
    int lg   = lane & 31;
    int grp  = threadIdx.x >> 5;
    int sh   = lane & 32;

    for (int node = blockIdx.x * 8 + grp; node < n; node += gridDim.x * 8) {
        int e0 = offs[node], e1 = offs[node + 1];
        float acc[LC];
#pragma unroll
        for (int a = 0; a < LC; a++) acc[a] = 0.f;
        float vsum = 0.f;

        for (int e = e0; e < e1; e += 32) {
            int   idx = e + lg;
            int2  cv = (idx < e1) ? cvA[idx] : make_int2(0, 0);
            int   ce = cv.x;
            float ve = __int_as_float(cv.y);
            int   cnt = min(32, e1 - e);
#pragma unroll 8
            for (int j = 0; j < cnt; j++) {
                int   c = __shfl(ce, sh + j);
                float v = __shfl(ve, sh + j);
                const float* srow = S + (size_t)c * ldS + LC * lg;
                if (LC == 3) {
                    f3u g = *(const f3u*)srow;
                    acc[0] = fmaf(v, g[0], acc[0]);
                    acc[1] = fmaf(v, g[1], acc[1]);
                    acc[2] = fmaf(v, g[2], acc[2]);
                } else {
                    f4u g = *(const f4u*)srow;
                    acc[0] = fmaf(v, g[0], acc[0]);
                    acc[1] = fmaf(v, g[1], acc[1]);
                    acc[2] = fmaf(v, g[2], acc[2]);
                    acc[3] = fmaf(v, g[3], acc[3]);
                }
                vsum += v;
            }
        }

        float* orow = Aout + (size_t)node * (32 * LC) + LC * lg;
        if (LC == 3) {
            f3u o; o[0] = acc[0]; o[1] = acc[1]; o[2] = acc[2];
            *(f3u*)orow = o;
        } else {
            f4u o; o[0] = acc[0]; o[1] = acc[1]; o[2] = acc[2]; o[3] = acc[3];
            *(f4u*)orow = o;
        }
        if (WVS && lg == 0) vout[node] = vsum;
    }
}

// ===== aggB: gather 96-wide + bias + relu + BN partials + vsum (layer-1 tail) =====
__global__ __launch_bounds__(256)
void aggB(const float* __restrict__ S, const int* __restrict__ offs,
          const int2* __restrict__ cvA, const float* __restrict__ bias,
          float* __restrict__ Hout, float* __restrict__ vout,
          float* __restrict__ pbuf, int n) {
    __shared__ float sS[96], sQ[96];
    int t = threadIdx.x;
    if (t < 96) { sS[t] = 0.f; sQ[t] = 0.f; }
    __syncthreads();
    int lane = t & 63, lg = lane & 31, grp = t >> 5, sh = lane & 32;
    float bb[3];
    bb[0] = bias[3 * lg]; bb[1] = bias[3 * lg + 1]; bb[2] = bias[3 * lg + 2];
    float ps[3] = {0.f, 0.f, 0.f}, pq[3] = {0.f, 0.f, 0.f};

    for (int node = blockIdx.x * 8 + grp; node < n; node += gridDim.x * 8) {
        int e0 = offs[node], e1 = offs[node + 1];
        float acc[3] = {0.f, 0.f, 0.f};
        float vsum = 0.f;
        for (int e = e0; e < e1; e += 32) {
            int   idx = e + lg;
            int2  cv = (idx < e1) ? cvA[idx] : make_int2(0, 0);
            int   ce = cv.x;
            float ve = __int_as_float(cv.y);
            int   cnt = min(32, e1 - e);
#pragma unroll 8
            for (int j = 0; j < cnt; j++) {
                int   c = __shfl(ce, sh + j);
                float v = __shfl(ve, sh + j);
                const float* srow = S + (size_t)c * 96 + 3 * lg;
                f3u g = *(const f3u*)srow;
                acc[0] = fmaf(v, g[0], acc[0]);
                acc[1] = fmaf(v, g[1], acc[1]);
                acc[2] = fmaf(v, g[2], acc[2]);
                vsum += v;
            }
        }
        float* orow = Hout + (size_t)node * 96 + 3 * lg;
        f3u o;
#pragma unroll
        for (int a = 0; a < 3; a++) {
            float v = fmaxf(acc[a] + bb[a], 0.f);
            o[a] = v;
            ps[a] += v; pq[a] += v * v;
        }
        *(f3u*)orow = o;
        if (lg == 0) vout[node] = vsum;
    }
#pragma unroll
    for (int a = 0; a < 3; a++) {
        atomicAdd(&sS[3 * lg + a], ps[a]);
        atomicAdd(&sQ[3 * lg + a], pq[a]);
    }
    __syncthreads();
    if (t < 96) {
        pbuf[(size_t)blockIdx.x * 192 + t]      = sS[t];
        pbuf[(size_t)blockIdx.x * 192 + 96 + t] = sQ[t];
    }
}

// reduce pbuf[nb][192] -> stats[192]
__global__ __launch_bounds__(256)
void bn_reduce(const float* __restrict__ pbuf, float* __restrict__ stats, int nb) {
    int t = threadIdx.x;
    if (t < 192) {
        float s = 0.f;
        for (int pb = blockIdx.x; pb < nb; pb += gridDim.x)
            s += pbuf[(size_t)pb * 192 + t];
        atomicAdd(&stats[t], s);
    }
}

// ===== aggC: gather 64-wide + relu(acc + vsum*cb + bias) (layer-5 tail) =====
__global__ __launch_bounds__(256)
void aggC(const float* __restrict__ S, const int* __restrict__ offs,
          const int2* __restrict__ cvA, const float* __restrict__ bias,
          const float* __restrict__ cb, const float* __restrict__ vsum,
          float* __restrict__ Hout, int n) {
    int lane = threadIdx.x & 63, lg = lane & 31, grp = threadIdx.x >> 5, sh = lane & 32;
    float bb0 = bias[2 * lg], bb1 = bias[2 * lg + 1];
    float cc0 = cb[2 * lg],   cc1 = cb[2 * lg + 1];

    for (int node = blockIdx.x * 8 + grp; node < n; node += gridDim.x * 8) {
        int e0 = offs[node], e1 = offs[node + 1];
        float a0 = 0.f, a1 = 0.f;
        for (int e = e0; e < e1; e += 32) {
            int   idx = e + lg;
            int2  cv = (idx < e1) ? cvA[idx] : make_int2(0, 0);
            int   ce = cv.x;
            float ve = __int_as_float(cv.y);
            int   cnt = min(32, e1 - e);
#pragma unroll 8
            for (int j = 0; j < cnt; j++) {
                int   c = __shfl(ce, sh + j);
                float v = __shfl(ve, sh + j);
                f2a g = *(const f2a*)(S + (size_t)c * 64 + 2 * lg);
                a0 = fmaf(v, g[0], a0);
                a1 = fmaf(v, g[1], a1);
            }
        }
        float vs = vsum[node];
        f2a o;
        o[0] = fmaxf(a0 + vs * cc0 + bb0, 0.f);
        o[1] = fmaxf(a1 + vs * cc1 + bb1, 0.f);
        *(f2a*)(Hout + (size_t)node * 64 + 2 * lg) = o;
    }
}

// ============================ Tiled GEMM v2: 64-row tile, K-chunk 16 ============================
template <int CT>
__device__ inline void ldw(const float* p, float* wv) {
    if constexpr (CT == 4) { *(f4a*)wv = *(const f4a*)p; }
    else if constexpr (CT == 6) { *(f3u*)wv = *(const f3u*)p; *(f3u*)(wv + 3) = *(const f3u*)(p + 3); }
    else { *(f4a*)wv = *(const f4a*)p; *(f4a*)(wv + 4) = *(const f4a*)(p + 4); }
}

// DOT mode (C=64 only): m[r] = sum_c relu(acc[r][c]+bias[c]) * cbv[c] + vsum[0];
template <int K, int C, bool DOBN, bool HASCB, bool LIN = false, bool DOT = false>
__global__ __launch_bounds__(256)
void gemmF(const float* __restrict__ A1, int ld1, int split,
           const float* __restrict__ A2, int ld2,
           const float* __restrict__ W, const float* __restrict__ bias,
           const float* __restrict__ cbv, const float* __restrict__ vsum,
           float* __restrict__ Out, float* __restrict__ bsum,
           float* __restrict__ bsumsq, int n) {
    constexpr int CT = C / 16;           // 4, 6, or 8
    __shared__ float Wc[16 * C];
    __shared__ float At[16][68];
    __shared__ float redS[DOBN ? C : 1];
    __shared__ float redQ[DOBN ? C : 1];

    int t  = threadIdx.x;
    int tc = t & 15, tr = t >> 4;
    int row0 = blockIdx.x * 64;

    if (DOBN && t < C) { redS[t] = 0.f; redQ[t] = 0.f; }

    int srow = t >> 2;
    int gr = row0 + srow; if (gr >= n) gr = n - 1;
    int kh = (t & 3) * 4;

    float acc[4][CT];
#pragma unroll
    for (int i = 0; i < 4; i++)
#pragma unroll
        for (int c = 0; c < CT; c++) acc[i][c] = 0.f;

    for (int kb = 0; kb < K; kb += 16) {
        __syncthreads();
        for (int i = t * 4; i < 16 * C; i += 1024)
            *(f4a*)&Wc[i] = *(const f4u*)&W[(size_t)kb * C + i];
        {
            int kg = kb + kh;
            const float* src = (kg < split) ? (A1 + (size_t)gr * ld1 + kg)
                                            : (A2 + (size_t)gr * ld2 + (kg - split));
            f4u v = *(const f4u*)src;
#pragma unroll
            for (int e = 0; e < 4; e++) At[kh + e][srow] = v[e];
        }
        __syncthreads();
#pragma unroll
        for (int kk = 0; kk < 16; kk++) {
            f4a av = *(const f4a*)&At[kk][tr * 4];
            float wv[CT];
            ldw<CT>(&Wc[kk * C + tc * CT], wv);
#pragma unroll
            for (int i = 0; i < 4; i++)
#pragma unroll
                for (int c = 0; c < CT; c++) acc[i][c] = fmaf(av[i], wv[c], acc[i][c]);
        }
    }

    if constexpr (DOT) {
        // bias = M2b, cbv = M3w (64), vsum = M3b (1), Out = m, bsum = (float*)gmin
        float bb2[CT], ww[CT];
#pragma unroll
        for (int c = 0; c < CT; c++) { bb2[c] = bias[tc * CT + c]; ww[c] = cbv[tc * CT + c]; }
        float b3 = vsum[0];
        float lmin = 3.4e38f;
#pragma unroll
        for (int i = 0; i < 4; i++) {
            float d = 0.f;
#pragma unroll
            for (int c = 0; c < CT; c++) d = fmaf(fmaxf(acc[i][c] + bb2[c], 0.f), ww[c], d);
            d += __shfl_xor(d, 1); d += __shfl_xor(d, 2);
            d += __shfl_xor(d, 4); d += __shfl_xor(d, 8);
            int r = row0 + tr * 4 + i;
            if (tc == 0 && r < n) {
                float mv = d + b3;
                Out[r] = mv;
                lmin = fminf(lmin, mv);
            }
        }
        __shared__ float smin[16];
        if (tc == 0) smin[tr] = lmin;
        __syncthreads();
        if (t == 0) {
            float mn = smin[0];
#pragma unroll
            for (int i2 = 1; i2 < 16; i2++) mn = fminf(mn, smin[i2]);
            unsigned u = __float_as_uint(mn);
            unsigned key = (u >> 31) ? ~u : (u | 0x80000000u);
            atomicMin((unsigned*)bsum, key);
        }
        return;
    }

    float bb[CT], cc[CT];
#pragma unroll
    for (int c = 0; c < CT; c++) {
        bb[c] = LIN ? 0.f : bias[tc * CT + c];
        cc[c] = HASCB ? cbv[tc * CT + c] : 0.f;
    }
    float ps[CT], pq[CT];
#pragma unroll
    for (int c = 0; c < CT; c++) { ps[c] = 0.f; pq[c] = 0.f; }

#pragma unroll
    for (int i = 0; i < 4; i++) {
        int r = row0 + tr * 4 + i;
        if (r < n) {
            float vs = HASCB ? vsum[r] : 0.f;
            float* o = Out + (size_t)r * C + tc * CT;
#pragma unroll
            for (int c = 0; c < CT; c++) {
                float v = acc[i][c] + vs * cc[c] + bb[c];
                if (!LIN) v = fmaxf(v, 0.f);
                o[c] = v;
                if (DOBN) { ps[c] += v; pq[c] += v * v; }
            }
        }
    }
    if (DOBN) {
#pragma unroll
        for (int c = 0; c < CT; c++) {
            ps[c] += __shfl_xor(ps[c], 16);
            ps[c] += __shfl_xor(ps[c], 32);
            pq[c] += __shfl_xor(pq[c], 16);
            pq[c] += __shfl_xor(pq[c], 32);
        }
        if ((t & 48) == 0) {
#pragma unroll
            for (int c = 0; c < CT; c++) {
                atomicAdd(&redS[tc * CT + c], ps[c]);
                atomicAdd(&redQ[tc * CT + c], pq[c]);
            }
        }
        __syncthreads();
        if (t < C) {
            atomicAdd(&bsum[t], redS[t]);
            atomicAdd(&bsumsq[t], redQ[t]);
        }
    }
}

// ============================ BN fold ============================
template <int C>
__global__ __launch_bounds__(256)
void fold_kernel(const float* __restrict__ W, float* __restrict__ bsum,
                 float* __restrict__ bsumsq, float* __restrict__ Wf,
                 float* __restrict__ cb, int N) {
    __shared__ float mean[96], inv[96];
    int t = threadIdx.x;
    float rn = 1.0f / (float)N;
    if (t < 96) {
        float mu  = bsum[t] * rn;
        float var = bsumsq[t] * rn - mu * mu;
        mean[t] = mu;
        inv[t]  = rsqrtf(var + 1e-5f);
        bsum[t] = 0.f;
        bsumsq[t] = 0.f;
    }
    __syncthreads();
    for (int i = t; i < 96 * C; i += 256) {
        int k = i / C;
        Wf[i] = inv[k] * W[i];
    }
    if (t < C) {
        float s = 0.f;
        for (int k = 0; k < 96; k++) s += mean[k] * inv[k] * W[k * C + t];
        cb[t] = -s;
    }
}

// ============================ exact select: two-level LDS radix ============================
__device__ inline unsigned fkey(float f) {
    unsigned u = __float_as_uint(f);
    return (u >> 31) ? ~u : (u | 0x80000000u);
}

__global__ __launch_bounds__(256)
void where_hist(const float* __restrict__ x, float* __restrict__ m,
                const unsigned* __restrict__ gmin, unsigned* __restrict__ h0, int n) {
    __shared__ unsigned lh[256];
    int t = threadIdx.x;
    lh[t] = 0u;
    __syncthreads();
    unsigned k = *gmin;
    unsigned u = (k >> 31) ? (k ^ 0x80000000u) : ~k;
    float g = __uint_as_float(u);
    for (int i = blockIdx.x * 256 + t; i < n; i += gridDim.x * 256) {
        float mv = m[i];
        if (x[(size_t)i * XLD + 160] == 0.0f) { mv = g; m[i] = mv; }
        atomicAdd(&lh[fkey(mv) >> 24], 1u);
    }
    __syncthreads();
    if (lh[t]) atomicAdd(&h0[t], lh[t]);
}

__global__ __launch_bounds__(256)
void sel_pick8(const unsigned* __restrict__ h, const unsigned* __restrict__ kres,
               int kconst, unsigned* __restrict__ outb, unsigned* __restrict__ outk) {
    int t = threadIdx.x;
    int bin = 255 - t;
    unsigned k = kres ? *kres : (unsigned)kconst;
    unsigned c = h[bin];
    unsigned x = c;
#pragma unroll
    for (int o = 1; o < 64; o <<= 1) { unsigned y = __shfl_up(x, o); if ((t & 63) >= o) x += y; }
    __shared__ unsigned ws[4];
    if ((t & 63) == 63) ws[t >> 6] = x;
    __syncthreads();
    unsigned add = 0;
    for (int w = 0; w < (t >> 6); w++) add += ws[w];
    unsigned incl = x + add, excl = incl - c;
    if (excl < k && k <= incl) { *outb = (unsigned)bin; *outk = k - excl; }
}

__global__ __launch_bounds__(256)
void sel_hist8b(const float* __restrict__ m, const unsigned* __restrict__ pick,
                unsigned* __restrict__ h1, int n) {
    __shared__ unsigned lh[256];
    int t = threadIdx.x;
    lh[t] = 0u;
    __syncthreads();
    unsigned b0 = pick[0];
    for (int i = blockIdx.x * 256 + t; i < n; i += gridDim.x * 256) {
        unsigned key = fkey(m[i]);
        if ((key >> 24) == b0) atomicAdd(&lh[(key >> 16) & 255u], 1u);
    }
    __syncthreads();
    if (lh[t]) atomicAdd(&h1[t], lh[t]);
}

__global__ void sel_collect(const float* __restrict__ m, const unsigned* __restrict__ pick,
                            unsigned* __restrict__ sbuf, unsigned* __restrict__ scnt, int n) {
    unsigned pfx = (pick[0] << 8) | pick[2];
    for (int i = blockIdx.x * blockDim.x + threadIdx.x; i < n; i += gridDim.x * blockDim.x) {
        unsigned key = fkey(m[i]);
        if ((key >> 16) == pfx) sbuf[atomicAdd(scnt, 1u)] = key;
    }
}

__global__ __launch_bounds__(1024)
void sel_final(const unsigned* __restrict__ sbuf, const unsigned* __restrict__ scnt,
               const unsigned* __restrict__ pick, float* __restrict__ thresh) {
    __shared__ unsigned hist[256];
    __shared__ unsigned spfx;
    __shared__ int skk;
    int t = threadIdx.x;
    int ns = (int)*scnt;
    if (t == 0) { spfx = ((pick[0] << 8) | pick[2]) << 16; skk = (int)pick[3]; }
    __syncthreads();
    for (int pass = 0; pass < 2; ++pass) {
        if (t < 256) hist[t] = 0u;
        __syncthreads();
        int shift = 8 - 8 * pass;
        unsigned pfxmask = (pass == 0) ? 0xFFFF0000u : 0xFFFFFF00u;
        unsigned pfx = spfx;
        for (int i = t; i < ns; i += 1024) {
            unsigned key = sbuf[i];
            if ((key & pfxmask) == pfx) atomicAdd(&hist[(key >> shift) & 255u], 1u);
        }
        __syncthreads();
        if (t == 0) {
            int cum = 0, kk = skk, chosen = 0;
            for (int b = 255; b >= 0; b--) {
                cum += (int)hist[b];
                if (cum >= kk) { chosen = b; kk -= (cum - (int)hist[b]); break; }
            }
            spfx = pfx | ((unsigned)chosen << shift);
            skk = kk;
        }
        __syncthreads();
    }
    if (t == 0) {
        unsigned key = spfx;
        unsigned u = (key >> 31) ? (key ^ 0x80000000u) : ~key;
        *thresh = __uint_as_float(u);
    }
}

__global__ void mask_kernel(const float* __restrict__ m, const float* __restrict__ thresh,
                            float* __restrict__ out, int n) {
    int i = blockIdx.x * blockDim.x + threadIdx.x;
    if (i < n) {
        float t = *thresh, v = m[i];
        out[i] = (v > t) ? v * (1.0f / v) : 0.0f;
    }
}

// ============================ launch ============================
extern "C" void kernel_launch(void* const* d_in, const int* in_sizes, int n_in,
                              void* d_out, int out_size, void* d_ws, size_t ws_size,
                              hipStream_t stream) {
    const float* x   = (const float*)d_in[0];
    const int*   row = (const int*)d_in[1];
    const int*   col = (const int*)d_in[2];
    const float* val = (const float*)d_in[3];
    const float* W1  = (const float*)d_in[4];
    const float* b1  = (const float*)d_in[5];
    const float* W2  = (const float*)d_in[6];
    const float* b2  = (const float*)d_in[7];
    const float* W3  = (const float*)d_in[8];
    const float* b3  = (const float*)d_in[9];
    const float* W4  = (const float*)d_in[10];
    const float* b4  = (const float*)d_in[11];
    const float* W5  = (const float*)d_in[12];
    const float* b5  = (const float*)d_in[13];
    const float* M1w = (const float*)d_in[14];
    const float* M1b = (const float*)d_in[15];
    const float* M2w = (const float*)d_in[16];
    const float* M2b = (const float*)d_in[17];
    const float* M3w = (const float*)d_in[18];
    const float* M3b = (const float*)d_in[19];

    const int n = in_sizes[0] / XLD;   // 50000
    const int E = in_sizes[1];         // 800000

    char* ws = (char*)d_ws;
    size_t off = 0;
    auto carve = [&](size_t bytes) -> void* {
        void* p = ws + off;
        off = (off + bytes + 255) & ~(size_t)255;
        return p;
    };
    int*      offs   = (int*)carve((size_t)(n + 1) * 4);
    int*      cursor = (int*)carve((size_t)n * 4);
    int*      bsums  = (int*)carve(256 * 4);
    int2*     cvA    = (int2*)carve((size_t)E * 8);
    float*    hA     = (float*)carve((size_t)n * 128 * 4);   // buffer A
    float*    hB     = (float*)carve((size_t)n * 128 * 4);   // buffer B
    float*    Wf     = (float*)carve(96 * 96 * 4);
    float*    stats  = (float*)carve(192 * 4);
    float*    cb     = (float*)carve(96 * 4);
    float*    vsum   = (float*)carve((size_t)n * 4);
    float*    m      = (float*)carve((size_t)n * 4);
    unsigned* gmin   = (unsigned*)carve(4);
    float*    thresh = (float*)carve(4);
    unsigned* h0     = (unsigned*)carve(256 * 4);
    unsigned* h1     = (unsigned*)carve(256 * 4);
    unsigned* sbuf   = (unsigned*)carve((size_t)n * 4);
    unsigned* scnt   = (unsigned*)carve(4);
    unsigned* pick   = (unsigned*)carve(16);
    float*    pbuf   = (float*)carve((size_t)GA * 192 * 4);
    float* bsum   = stats;
    float* bsumsq = stats + 96;

    hipMemsetAsync(cursor, 0, (size_t)n * 4, stream);
    hipMemsetAsync(stats, 0, 192 * 4, stream);
    hipMemsetAsync(gmin, 0xFF, 4, stream);
    hipMemsetAsync(h0, 0, 256 * 4, stream);
    hipMemsetAsync(h1, 0, 256 * 4, stream);
    hipMemsetAsync(scnt, 0, 4, stream);

    // CSR build
    const int nb = (n + 255) / 256;
    hist_kernel<<<2048, 256, 0, stream>>>(row, cursor, E);
    scan1_kernel<<<nb, 256, 0, stream>>>(cursor, offs, bsums, n);
    scan2_kernel<<<1, 256, 0, stream>>>(bsums, nb);
    scan3_kernel<<<nb, 256, 0, stream>>>(offs, cursor, bsums, n, E);
    scatter_kernel<<<2048, 256, 0, stream>>>(row, col, val, cursor, cvA, E);

    const int gB = (n + 63) / 64;       // gemmF row tiles (782)

    // Layer 1 (multiply-first): s1 = x[:,:128] @ W1 (linear) -> hB; h1 = relu(agg(s1)+b1) -> hA
    gemmF<128, 96, false, false, true><<<gB, 256, 0, stream>>>(x, XLD, 128, x, XLD,
        W1, b1, nullptr, nullptr, hB, bsum, bsumsq, n);
    aggB<<<GA, 256, 0, stream>>>(hB, offs, cvA, b1, hA, vsum, pbuf, n);
    bn_reduce<<<64, 256, 0, stream>>>(pbuf, stats, GA);

    // Layers 2-4: split gather + GEMM, ping-pong
    fold_kernel<96><<<1, 256, 0, stream>>>(W2, bsum, bsumsq, Wf, cb, n);
    aggP<3, false><<<GA, 256, 0, stream>>>(hA, 96, offs, cvA, hB, nullptr, n);
    gemmF<96, 96, true, true><<<gB, 256, 0, stream>>>(hB, 96, 96, hB, 96,
        Wf, b2, cb, vsum, hA, bsum, bsumsq, n);

    fold_kernel<96><<<1, 256, 0, stream>>>(W3, bsum, bsumsq, Wf, cb, n);
    aggP<3, false><<<GA, 256, 0, stream>>>(hA, 96, offs, cvA, hB, nullptr, n);
    gemmF<96, 96, true, true><<<gB, 256, 0, stream>>>(hB, 96, 96, hB, 96,
        Wf, b3, cb, vsum, hA, bsum, bsumsq, n);

    fold_kernel<96><<<1, 256, 0, stream>>>(W4, bsum, bsumsq, Wf, cb, n);
    aggP<3, false><<<GA, 256, 0, stream>>>(hA, 96, offs, cvA, hB, nullptr, n);
    gemmF<96, 96, true, true><<<gB, 256, 0, stream>>>(hB, 96, 96, hB, 96,
        Wf, b4, cb, vsum, hA, bsum, bsumsq, n);

    // Layer 5 (multiply-first): s5 = h4 @ W5f (linear, n x 64) -> hB; h5 = relu(agg(s5)+vsum*cb+b5) -> hA
    fold_kernel<64><<<1, 256, 0, stream>>>(W5, bsum, bsumsq, Wf, cb, n);
    gemmF<96, 64, false, false, true><<<gB, 256, 0, stream>>>(hA, 96, 96, hA, 96,
        Wf, b5, nullptr, nullptr, hB, bsum, bsumsq, n);
    aggC<<<GA, 256, 0, stream>>>(hB, offs, cvA, b5, cb, vsum, hA, n);

    // MLP
    gemmF<96, 128, false, false><<<gB, 256, 0, stream>>>(hA, 64, 64, x + 128, XLD,
        M1w, M1b, nullptr, nullptr, hB, bsum, bsumsq, n);
    gemmF<128, 64, false, false, false, true><<<gB, 256, 0, stream>>>(hB, 128, 128, hB, 128,
        M2w, M2b, M3w, M3b, m, (float*)gmin, nullptr, n);

    // where(grp==0, min, m) fused with level-0 select histogram
    where_hist<<<64, 256, 0, stream>>>(x, m, gmin, h0, n);

    // exact 71st-largest threshold (two-level LDS radix)
    sel_pick8<<<1, 256, 0, stream>>>(h0, nullptr, 71, &pick[0], &pick[1]);
    sel_hist8b<<<64, 256, 0, stream>>>(m, pick, h1, n);
    sel_pick8<<<1, 256, 0, stream>>>(h1, &pick[1], 0, &pick[2], &pick[3]);
    sel_collect<<<64, 256, 0, stream>>>(m, pick, sbuf, scnt, n);
    sel_final<<<1, 1024, 0, stream>>>(sbuf, scnt, pick, thresh);

    // out = m>thresh ? m*(1/m) : 0
    mask_kernel<<<(n + 255) / 256, 256, 0, stream>>>(m, thresh, (float*)d_out, n);
}

// Round 16
// 689.975 us; speedup vs baseline: 1.1589x; 1.0507x over previous
//
#include <hip/hip_runtime.h>
#include <cstdint>
#include <cstddef>

#define XLD 161   // x row stride = NFEAT + EXTRA + 1
#define GA  2048  // agg grid: 8 blocks/CU x 256 CU
#define SBCAP 6144  // scatterB LDS stage capacity (mean bucket 4082, sd 64)

typedef float f4u __attribute__((ext_vector_type(4), aligned(4)));  // unaligned-tolerant
typedef float f4a __attribute__((ext_vector_type(4)));              // 16B-aligned
typedef float f3u __attribute__((ext_vector_type(3), aligned(4)));
typedef float f2a __attribute__((ext_vector_type(2)));              // 8B-aligned

// ============================ CSR build ============================
__global__ void hist_kernel(const int* __restrict__ row, int* __restrict__ cnt, int E) {
    for (int e = blockIdx.x * blockDim.x + threadIdx.x; e < E; e += gridDim.x * blockDim.x)
        atomicAdd(&cnt[row[e]], 1);
}

__global__ __launch_bounds__(256)
void scan1_kernel(const int* __restrict__ cnt, int* __restrict__ offs,
                  int* __restrict__ bsums, int n) {
    int t = threadIdx.x;
    int gid = blockIdx.x * 256 + t;
    int v = (gid < n) ? cnt[gid] : 0;
    int x = v;
#pragma unroll
    for (int o = 1; o < 64; o <<= 1) { int y = __shfl_up(x, o); if ((t & 63) >= o) x += y; }
    __shared__ int ws[4];
    if ((t & 63) == 63) ws[t >> 6] = x;
    __syncthreads();
    int add = 0;
    for (int w = 0; w < (t >> 6); w++) add += ws[w];
    int incl = x + add;
    if (gid < n) offs[gid] = incl - v;
    if (t == 255) bsums[blockIdx.x] = incl;
}

__global__ __launch_bounds__(256)
void scan2_kernel(int* __restrict__ bsums, int nb) {
    int t = threadIdx.x;
    int v = (t < nb) ? bsums[t] : 0;
    int x = v;
#pragma unroll
    for (int o = 1; o < 64; o <<= 1) { int y = __shfl_up(x, o); if ((t & 63) >= o) x += y; }
    __shared__ int ws[4];
    if ((t & 63) == 63) ws[t >> 6] = x;
    __syncthreads();
    int add = 0;
    for (int w = 0; w < (t >> 6); w++) add += ws[w];
    if (t < nb) bsums[t] = x + add - v;
}

__global__ void scan3_kernel(int* __restrict__ offs, int* __restrict__ cursor,
                             const int* __restrict__ bsums, int* __restrict__ bcur,
                             int n, int E) {
    int gid = blockIdx.x * 256 + threadIdx.x;
    if (gid < n) {
        int o = offs[gid] + bsums[blockIdx.x];
        offs[gid] = o;
        cursor[gid] = o;
        if ((gid & 255) == 0) bcur[gid >> 8] = o;   // bucket base cursor
    }
    if (gid == 0) offs[n] = E;
}

// ===== scatterA: bucket edges (b = row>>8) into tmpE with per-block range reservation =====
// Each block: 2048 edges; LDS count per bucket -> 1 global atomic per bucket -> grouped writes
// (runs of ~10 edges per bucket per block => ~full dirty lines instead of 8B/line).
__global__ __launch_bounds__(256)
void scatterA(const int* __restrict__ row, const int* __restrict__ col,
              const float* __restrict__ val, int* __restrict__ bcur,
              int4* __restrict__ tmpE, int E, int nbk) {
    __shared__ int cntL[256], baseL[256], rankL[256];
    int t = threadIdx.x;
    cntL[t] = 0; rankL[t] = 0;
    __syncthreads();
    int e0 = blockIdx.x * 2048;
    int r[8], b[8];
#pragma unroll
    for (int j = 0; j < 8; j++) {
        int e = e0 + j * 256 + t;
        if (e < E) { r[j] = row[e]; b[j] = r[j] >> 8; atomicAdd(&cntL[b[j]], 1); }
        else { r[j] = -1; b[j] = 0; }
    }
    __syncthreads();
    if (t < nbk && cntL[t]) baseL[t] = atomicAdd(&bcur[t], cntL[t]);
    __syncthreads();
#pragma unroll
    for (int j = 0; j < 8; j++) {
        int e = e0 + j * 256 + t;
        if (e < E) {
            int q = atomicAdd(&rankL[b[j]], 1);
            tmpE[baseL[b[j]] + q] = make_int4(r[j], col[e], __float_as_int(val[e]), 0);
        }
    }
}

// ===== scatterB: per-bucket LDS scatter to exact CSR order; coalesced final writes =====
__global__ __launch_bounds__(256)
void scatterB(const int4* __restrict__ tmpE, const int* __restrict__ offs,
              int* __restrict__ gcur, int2* __restrict__ cvA, int n) {
    __shared__ int cur[256];
    __shared__ int2 stage[SBCAP];
    int b = blockIdx.x, t = threadIdx.x;
    int rowLo = b << 8;
    int rowHi = min(n, rowLo + 256);
    int base = offs[rowLo];
    int end  = offs[rowHi];
    int len  = end - base;
    if (rowLo + t < rowHi) cur[t] = offs[rowLo + t] - base;
    __syncthreads();
    if (len <= SBCAP) {
        for (int i = t; i < len; i += 256) {
            int4 ed = tmpE[base + i];
            int q = atomicAdd(&cur[ed.x - rowLo], 1);
            stage[q] = make_int2(ed.y, ed.z);
        }
        __syncthreads();
        for (int i = t; i < len; i += 256)
            cvA[base + i] = stage[i];
    } else {   // statistically unreachable fallback: global-cursor scatter
        for (int i = t; i < len; i += 256) {
            int4 ed = tmpE[base + i];
            int p = atomicAdd(&gcur[ed.x], 1);
            cvA[p] = make_int2(ed.y, ed.z);
        }
    }
}

// ============================ Pure aggregation ============================
template <int LC, bool WVS>   // LC floats per lane; row width = 32*LC
__global__ __launch_bounds__(256)
void aggP(const float* __restrict__ S, int ldS, const int* __restrict__ offs,
          const int2* __restrict__ cvA,
          float* __restrict__ Aout, float* __restrict__ vout, int n) {
    int lane = threadIdx.x & 63;
    int lg   = lane & 31;
    int grp  = threadIdx.x >> 5;
    int sh   = lane & 32;

    for (int node = blockIdx.x * 8 + grp; node < n; node += gridDim.x * 8) {
        int e0 = offs[node], e1 = offs[node + 1];
        float acc[LC];
#pragma unroll
        for (int a = 0; a < LC; a++) acc[a] = 0.f;
        float vsum = 0.f;

        for (int e = e0; e < e1; e += 32) {
            int   idx = e + lg;
            int2  cv = (idx < e1) ? cvA[idx] : make_int2(0, 0);
            int   ce = cv.x;
            float ve = __int_as_float(cv.y);
            int   cnt = min(32, e1 - e);
#pragma unroll 8
            for (int j = 0; j < cnt; j++) {
                int   c = __shfl(ce, sh + j);
                float v = __shfl(ve, sh + j);
                const float* srow = S + (size_t)c * ldS + LC * lg;
                if (LC == 3) {
                    f3u g = *(const f3u*)srow;
                    acc[0] = fmaf(v, g[0], acc[0]);
                    acc[1] = fmaf(v, g[1], acc[1]);
                    acc[2] = fmaf(v, g[2], acc[2]);
                } else {
                    f4u g = *(const f4u*)srow;
                    acc[0] = fmaf(v, g[0], acc[0]);
                    acc[1] = fmaf(v, g[1], acc[1]);
                    acc[2] = fmaf(v, g[2], acc[2]);
                    acc[3] = fmaf(v, g[3], acc[3]);
                }
                vsum += v;
            }
        }

        float* orow = Aout + (size_t)node * (32 * LC) + LC * lg;
        if (LC == 3) {
            f3u o; o[0] = acc[0]; o[1] = acc[1]; o[2] = acc[2];
            *(f3u*)orow = o;
        } else {
            f4u o; o[0] = acc[0]; o[1] = acc[1]; o[2] = acc[2]; o[3] = acc[3];
            *(f4u*)orow = o;
        }
        if (WVS && lg == 0) vout[node] = vsum;
    }
}

// ===== aggB: gather 96-wide + bias + relu + BN partials + vsum (layer-1 tail) =====
__global__ __launch_bounds__(256)
void aggB(const float* __restrict__ S, const int* __restrict__ offs,
          const int2* __restrict__ cvA, const float* __restrict__ bias,
          float* __restrict__ Hout, float* __restrict__ vout,
          float* __restrict__ pbuf, int n) {
    __shared__ float sS[96], sQ[96];
    int t = threadIdx.x;
    if (t < 96) { sS[t] = 0.f; sQ[t] = 0.f; }
    __syncthreads();
    int lane = t & 63, lg = lane & 31, grp = t >> 5, sh = lane & 32;
    float bb[3];
    bb[0] = bias[3 * lg]; bb[1] = bias[3 * lg + 1]; bb[2] = bias[3 * lg + 2];
    float ps[3] = {0.f, 0.f, 0.f}, pq[3] = {0.f, 0.f, 0.f};

    for (int node = blockIdx.x * 8 + grp; node < n; node += gridDim.x * 8) {
        int e0 = offs[node], e1 = offs[node + 1];
        float acc[3] = {0.f, 0.f, 0.f};
        float vsum = 0.f;
        for (int e = e0; e < e1; e += 32) {
            int   idx = e + lg;
            int2  cv = (idx < e1) ? cvA[idx] : make_int2(0, 0);
            int   ce = cv.x;
            float ve = __int_as_float(cv.y);
            int   cnt = min(32, e1 - e);
#pragma unroll 8
            for (int j = 0; j < cnt; j++) {
                int   c = __shfl(ce, sh + j);
                float v = __shfl(ve, sh + j);
                const float* srow = S + (size_t)c * 96 + 3 * lg;
                f3u g = *(const f3u*)srow;
                acc[0] = fmaf(v, g[0], acc[0]);
                acc[1] = fmaf(v, g[1], acc[1]);
                acc[2] = fmaf(v, g[2], acc[2]);
                vsum += v;
            }
        }
        float* orow = Hout + (size_t)node * 96 + 3 * lg;
        f3u o;
#pragma unroll
        for (int a = 0; a < 3; a++) {
            float v = fmaxf(acc[a] + bb[a], 0.f);
            o[a] = v;
            ps[a] += v; pq[a] += v * v;
        }
        *(f3u*)orow = o;
        if (lg == 0) vout[node] = vsum;
    }
#pragma unroll
    for (int a = 0; a < 3; a++) {
        atomicAdd(&sS[3 * lg + a], ps[a]);
        atomicAdd(&sQ[3 * lg + a], pq[a]);
    }
    __syncthreads();
    if (t < 96) {
        pbuf[(size_t)blockIdx.x * 192 + t]      = sS[t];
        pbuf[(size_t)blockIdx.x * 192 + 96 + t] = sQ[t];
    }
}

// reduce pbuf[nb][192] -> stats[192]
__global__ __launch_bounds__(256)
void bn_reduce(const float* __restrict__ pbuf, float* __restrict__ stats, int nb) {
    int t = threadIdx.x;
    if (t < 192) {
        float s = 0.f;
        for (int pb = blockIdx.x; pb < nb; pb += gridDim.x)
            s += pbuf[(size_t)pb * 192 + t];
        atomicAdd(&stats[t], s);
    }
}

// ===== aggC: gather 64-wide + relu(acc + vsum*cb + bias) (layer-5 tail) =====
__global__ __launch_bounds__(256)
void aggC(const float* __restrict__ S, const int* __restrict__ offs,
          const int2* __restrict__ cvA, const float* __restrict__ bias,
          const float* __restrict__ cb, const float* __restrict__ vsum,
          float* __restrict__ Hout, int n) {
    int lane = threadIdx.x & 63, lg = lane & 31, grp = threadIdx.x >> 5, sh = lane & 32;
    float bb0 = bias[2 * lg], bb1 = bias[2 * lg + 1];
    float cc0 = cb[2 * lg],   cc1 = cb[2 * lg + 1];

    for (int node = blockIdx.x * 8 + grp; node < n; node += gridDim.x * 8) {
        int e0 = offs[node], e1 = offs[node + 1];
        float a0 = 0.f, a1 = 0.f;
        for (int e = e0; e < e1; e += 32) {
            int   idx = e + lg;
            int2  cv = (idx < e1) ? cvA[idx] : make_int2(0, 0);
            int   ce = cv.x;
            float ve = __int_as_float(cv.y);
            int   cnt = min(32, e1 - e);
#pragma unroll 8
            for (int j = 0; j < cnt; j++) {
                int   c = __shfl(ce, sh + j);
                float v = __shfl(ve, sh + j);
                f2a g = *(const f2a*)(S + (size_t)c * 64 + 2 * lg);
                a0 = fmaf(v, g[0], a0);
                a1 = fmaf(v, g[1], a1);
            }
        }
        float vs = vsum[node];
        f2a o;
        o[0] = fmaxf(a0 + vs * cc0 + bb0, 0.f);
        o[1] = fmaxf(a1 + vs * cc1 + bb1, 0.f);
        *(f2a*)(Hout + (size_t)node * 64 + 2 * lg) = o;
    }
}

// ============================ Tiled GEMM v2: 64-row tile, K-chunk 16 ============================
template <int CT>
__device__ inline void ldw(const float* p, float* wv) {
    if constexpr (CT == 4) { *(f4a*)wv = *(const f4a*)p; }
    else if constexpr (CT == 6) { *(f3u*)wv = *(const f3u*)p; *(f3u*)(wv + 3) = *(const f3u*)(p + 3); }
    else { *(f4a*)wv = *(const f4a*)p; *(f4a*)(wv + 4) = *(const f4a*)(p + 4); }
}

// DOT mode (C=64 only): m[r] = sum_c relu(acc[r][c]+bias[c]) * cbv[c] + vsum[0];
template <int K, int C, bool DOBN, bool HASCB, bool LIN = false, bool DOT = false>
__global__ __launch_bounds__(256)
void gemmF(const float* __restrict__ A1, int ld1, int split,
           const float* __restrict__ A2, int ld2,
           const float* __restrict__ W, const float* __restrict__ bias,
           const float* __restrict__ cbv, const float* __restrict__ vsum,
           float* __restrict__ Out, float* __restrict__ bsum,
           float* __restrict__ bsumsq, int n) {
    constexpr int CT = C / 16;           // 4, 6, or 8
    __shared__ float Wc[16 * C];
    __shared__ float At[16][68];
    __shared__ float redS[DOBN ? C : 1];
    __shared__ float redQ[DOBN ? C : 1];

    int t  = threadIdx.x;
    int tc = t & 15, tr = t >> 4;
    int row0 = blockIdx.x * 64;

    if (DOBN && t < C) { redS[t] = 0.f; redQ[t] = 0.f; }

    int srow = t >> 2;
    int gr = row0 + srow; if (gr >= n) gr = n - 1;
    int kh = (t & 3) * 4;

    float acc[4][CT];
#pragma unroll
    for (int i = 0; i < 4; i++)
#pragma unroll
        for (int c = 0; c < CT; c++) acc[i][c] = 0.f;

    for (int kb = 0; kb < K; kb += 16) {
        __syncthreads();
        for (int i = t * 4; i < 16 * C; i += 1024)
            *(f4a*)&Wc[i] = *(const f4u*)&W[(size_t)kb * C + i];
        {
            int kg = kb + kh;
            const float* src = (kg < split) ? (A1 + (size_t)gr * ld1 + kg)
                                            : (A2 + (size_t)gr * ld2 + (kg - split));
            f4u v = *(const f4u*)src;
#pragma unroll
            for (int e = 0; e < 4; e++) At[kh + e][srow] = v[e];
        }
        __syncthreads();
#pragma unroll
        for (int kk = 0; kk < 16; kk++) {
            f4a av = *(const f4a*)&At[kk][tr * 4];
            float wv[CT];
            ldw<CT>(&Wc[kk * C + tc * CT], wv);
#pragma unroll
            for (int i = 0; i < 4; i++)
#pragma unroll
                for (int c = 0; c < CT; c++) acc[i][c] = fmaf(av[i], wv[c], acc[i][c]);
        }
    }

    if constexpr (DOT) {
        // bias = M2b, cbv = M3w (64), vsum = M3b (1), Out = m, bsum = (float*)gmin
        float bb2[CT], ww[CT];
#pragma unroll
        for (int c = 0; c < CT; c++) { bb2[c] = bias[tc * CT + c]; ww[c] = cbv[tc * CT + c]; }
        float b3 = vsum[0];
        float lmin = 3.4e38f;
#pragma unroll
        for (int i = 0; i < 4; i++) {
            float d = 0.f;
#pragma unroll
            for (int c = 0; c < CT; c++) d = fmaf(fmaxf(acc[i][c] + bb2[c], 0.f), ww[c], d);
            d += __shfl_xor(d, 1); d += __shfl_xor(d, 2);
            d += __shfl_xor(d, 4); d += __shfl_xor(d, 8);
            int r = row0 + tr * 4 + i;
            if (tc == 0 && r < n) {
                float mv = d + b3;
                Out[r] = mv;
                lmin = fminf(lmin, mv);
            }
        }
        __shared__ float smin[16];
        if (tc == 0) smin[tr] = lmin;
        __syncthreads();
        if (t == 0) {
            float mn = smin[0];
#pragma unroll
            for (int i2 = 1; i2 < 16; i2++) mn = fminf(mn, smin[i2]);
            unsigned u = __float_as_uint(mn);
            unsigned key = (u >> 31) ? ~u : (u | 0x80000000u);
            atomicMin((unsigned*)bsum, key);
        }
        return;
    }

    float bb[CT], cc[CT];
#pragma unroll
    for (int c = 0; c < CT; c++) {
        bb[c] = LIN ? 0.f : bias[tc * CT + c];
        cc[c] = HASCB ? cbv[tc * CT + c] : 0.f;
    }
    float ps[CT], pq[CT];
#pragma unroll
    for (int c = 0; c < CT; c++) { ps[c] = 0.f; pq[c] = 0.f; }

#pragma unroll
    for (int i = 0; i < 4; i++) {
        int r = row0 + tr * 4 + i;
        if (r < n) {
            float vs = HASCB ? vsum[r] : 0.f;
            float* o = Out + (size_t)r * C + tc * CT;
#pragma unroll
            for (int c = 0; c < CT; c++) {
                float v = acc[i][c] + vs * cc[c] + bb[c];
                if (!LIN) v = fmaxf(v, 0.f);
                o[c] = v;
                if (DOBN) { ps[c] += v; pq[c] += v * v; }
            }
        }
    }
    if (DOBN) {
#pragma unroll
        for (int c = 0; c < CT; c++) {
            ps[c] += __shfl_xor(ps[c], 16);
            ps[c] += __shfl_xor(ps[c], 32);
            pq[c] += __shfl_xor(pq[c], 16);
            pq[c] += __shfl_xor(pq[c], 32);
        }
        if ((t & 48) == 0) {
#pragma unroll
            for (int c = 0; c < CT; c++) {
                atomicAdd(&redS[tc * CT + c], ps[c]);
                atomicAdd(&redQ[tc * CT + c], pq[c]);
            }
        }
        __syncthreads();
        if (t < C) {
            atomicAdd(&bsum[t], redS[t]);
            atomicAdd(&bsumsq[t], redQ[t]);
        }
    }
}

// ============================ BN fold ============================
template <int C>
__global__ __launch_bounds__(256)
void fold_kernel(const float* __restrict__ W, float* __restrict__ bsum,
                 float* __restrict__ bsumsq, float* __restrict__ Wf,
                 float* __restrict__ cb, int N) {
    __shared__ float mean[96], inv[96];
    int t = threadIdx.x;
    float rn = 1.0f / (float)N;
    if (t < 96) {
        float mu  = bsum[t] * rn;
        float var = bsumsq[t] * rn - mu * mu;
        mean[t] = mu;
        inv[t]  = rsqrtf(var + 1e-5f);
        bsum[t] = 0.f;
        bsumsq[t] = 0.f;
    }
    __syncthreads();
    for (int i = t; i < 96 * C; i += 256) {
        int k = i / C;
        Wf[i] = inv[k] * W[i];
    }
    if (t < C) {
        float s = 0.f;
        for (int k = 0; k < 96; k++) s += mean[k] * inv[k] * W[k * C + t];
        cb[t] = -s;
    }
}

// ============================ exact select: two-level LDS radix ============================
__device__ inline unsigned fkey(float f) {
    unsigned u = __float_as_uint(f);
    return (u >> 31) ? ~u : (u | 0x80000000u);
}

__global__ __launch_bounds__(256)
void where_hist(const float* __restrict__ x, float* __restrict__ m,
                const unsigned* __restrict__ gmin, unsigned* __restrict__ h0, int n) {
    __shared__ unsigned lh[256];
    int t = threadIdx.x;
    lh[t] = 0u;
    __syncthreads();
    unsigned k = *gmin;
    unsigned u = (k >> 31) ? (k ^ 0x80000000u) : ~k;
    float g = __uint_as_float(u);
    for (int i = blockIdx.x * 256 + t; i < n; i += gridDim.x * 256) {
        float mv = m[i];
        if (x[(size_t)i * XLD + 160] == 0.0f) { mv = g; m[i] = mv; }
        atomicAdd(&lh[fkey(mv) >> 24], 1u);
    }
    __syncthreads();
    if (lh[t]) atomicAdd(&h0[t], lh[t]);
}

__global__ __launch_bounds__(256)
void sel_pick8(const unsigned* __restrict__ h, const unsigned* __restrict__ kres,
               int kconst, unsigned* __restrict__ outb, unsigned* __restrict__ outk) {
    int t = threadIdx.x;
    int bin = 255 - t;
    unsigned k = kres ? *kres : (unsigned)kconst;
    unsigned c = h[bin];
    unsigned x = c;
#pragma unroll
    for (int o = 1; o < 64; o <<= 1) { unsigned y = __shfl_up(x, o); if ((t & 63) >= o) x += y; }
    __shared__ unsigned ws[4];
    if ((t & 63) == 63) ws[t >> 6] = x;
    __syncthreads();
    unsigned add = 0;
    for (int w = 0; w < (t >> 6); w++) add += ws[w];
    unsigned incl = x + add, excl = incl - c;
    if (excl < k && k <= incl) { *outb = (unsigned)bin; *outk = k - excl; }
}

__global__ __launch_bounds__(256)
void sel_hist8b(const float* __restrict__ m, const unsigned* __restrict__ pick,
                unsigned* __restrict__ h1, int n) {
    __shared__ unsigned lh[256];
    int t = threadIdx.x;
    lh[t] = 0u;
    __syncthreads();
    unsigned b0 = pick[0];
    for (int i = blockIdx.x * 256 + t; i < n; i += gridDim.x * 256) {
        unsigned key = fkey(m[i]);
        if ((key >> 24) == b0) atomicAdd(&lh[(key >> 16) & 255u], 1u);
    }
    __syncthreads();
    if (lh[t]) atomicAdd(&h1[t], lh[t]);
}

__global__ void sel_collect(const float* __restrict__ m, const unsigned* __restrict__ pick,
                            unsigned* __restrict__ sbuf, unsigned* __restrict__ scnt, int n) {
    unsigned pfx = (pick[0] << 8) | pick[2];
    for (int i = blockIdx.x * blockDim.x + threadIdx.x; i < n; i += gridDim.x * blockDim.x) {
        unsigned key = fkey(m[i]);
        if ((key >> 16) == pfx) sbuf[atomicAdd(scnt, 1u)] = key;
    }
}

__global__ __launch_bounds__(1024)
void sel_final(const unsigned* __restrict__ sbuf, const unsigned* __restrict__ scnt,
               const unsigned* __restrict__ pick, float* __restrict__ thresh) {
    __shared__ unsigned hist[256];
    __shared__ unsigned spfx;
    __shared__ int skk;
    int t = threadIdx.x;
    int ns = (int)*scnt;
    if (t == 0) { spfx = ((pick[0] << 8) | pick[2]) << 16; skk = (int)pick[3]; }
    __syncthreads();
    for (int pass = 0; pass < 2; ++pass) {
        if (t < 256) hist[t] = 0u;
        __syncthreads();
        int shift = 8 - 8 * pass;
        unsigned pfxmask = (pass == 0) ? 0xFFFF0000u : 0xFFFFFF00u;
        unsigned pfx = spfx;
        for (int i = t; i < ns; i += 1024) {
            unsigned key = sbuf[i];
            if ((key & pfxmask) == pfx) atomicAdd(&hist[(key >> shift) & 255u], 1u);
        }
        __syncthreads();
        if (t == 0) {
            int cum = 0, kk = skk, chosen = 0;
            for (int b = 255; b >= 0; b--) {
                cum += (int)hist[b];
                if (cum >= kk) { chosen = b; kk -= (cum - (int)hist[b]); break; }
            }
            spfx = pfx | ((unsigned)chosen << shift);
            skk = kk;
        }
        __syncthreads();
    }
    if (t == 0) {
        unsigned key = spfx;
        unsigned u = (key >> 31) ? (key ^ 0x80000000u) : ~key;
        *thresh = __uint_as_float(u);
    }
}

__global__ void mask_kernel(const float* __restrict__ m, const float* __restrict__ thresh,
                            float* __restrict__ out, int n) {
    int i = blockIdx.x * blockDim.x + threadIdx.x;
    if (i < n) {
        float t = *thresh, v = m[i];
        out[i] = (v > t) ? v * (1.0f / v) : 0.0f;
    }
}

// ============================ launch ============================
extern "C" void kernel_launch(void* const* d_in, const int* in_sizes, int n_in,
                              void* d_out, int out_size, void* d_ws, size_t ws_size,
                              hipStream_t stream) {
    const float* x   = (const float*)d_in[0];
    const int*   row = (const int*)d_in[1];
    const int*   col = (const int*)d_in[2];
    const float* val = (const float*)d_in[3];
    const float* W1  = (const float*)d_in[4];
    const float* b1  = (const float*)d_in[5];
    const float* W2  = (const float*)d_in[6];
    const float* b2  = (const float*)d_in[7];
    const float* W3  = (const float*)d_in[8];
    const float* b3  = (const float*)d_in[9];
    const float* W4  = (const float*)d_in[10];
    const float* b4  = (const float*)d_in[11];
    const float* W5  = (const float*)d_in[12];
    const float* b5  = (const float*)d_in[13];
    const float* M1w = (const float*)d_in[14];
    const float* M1b = (const float*)d_in[15];
    const float* M2w = (const float*)d_in[16];
    const float* M2b = (const float*)d_in[17];
    const float* M3w = (const float*)d_in[18];
    const float* M3b = (const float*)d_in[19];

    const int n = in_sizes[0] / XLD;   // 50000
    const int E = in_sizes[1];         // 800000
    const int nbk = (n + 255) >> 8;    // 196 buckets

    char* ws = (char*)d_ws;
    size_t off = 0;
    auto carve = [&](size_t bytes) -> void* {
        void* p = ws + off;
        off = (off + bytes + 255) & ~(size_t)255;
        return p;
    };
    int*      offs   = (int*)carve((size_t)(n + 1) * 4);
    int*      cursor = (int*)carve((size_t)n * 4);
    int*      bsums  = (int*)carve(256 * 4);
    int*      bcur   = (int*)carve(256 * 4);
    int2*     cvA    = (int2*)carve((size_t)E * 8);
    float*    hA     = (float*)carve((size_t)n * 128 * 4);   // buffer A (aliased as tmpE early)
    float*    hB     = (float*)carve((size_t)n * 128 * 4);   // buffer B
    float*    Wf     = (float*)carve(96 * 96 * 4);
    float*    stats  = (float*)carve(192 * 4);
    float*    cb     = (float*)carve(96 * 4);
    float*    vsum   = (float*)carve((size_t)n * 4);
    float*    m      = (float*)carve((size_t)n * 4);
    unsigned* gmin   = (unsigned*)carve(4);
    float*    thresh = (float*)carve(4);
    unsigned* h0     = (unsigned*)carve(256 * 4);
    unsigned* h1     = (unsigned*)carve(256 * 4);
    unsigned* sbuf   = (unsigned*)carve((size_t)n * 4);
    unsigned* scnt   = (unsigned*)carve(4);
    unsigned* pick   = (unsigned*)carve(16);
    float*    pbuf   = (float*)carve((size_t)GA * 192 * 4);
    float* bsum   = stats;
    float* bsumsq = stats + 96;
    int4*  tmpE   = (int4*)hA;   // 12.8 MB <= 25.6 MB; consumed before hA's first real write

    hipMemsetAsync(cursor, 0, (size_t)n * 4, stream);
    hipMemsetAsync(stats, 0, 192 * 4, stream);
    hipMemsetAsync(gmin, 0xFF, 4, stream);
    hipMemsetAsync(h0, 0, 256 * 4, stream);
    hipMemsetAsync(h1, 0, 256 * 4, stream);
    hipMemsetAsync(scnt, 0, 4, stream);

    // CSR build: hist -> scan -> bucketed two-pass scatter
    const int nb = (n + 255) / 256;
    hist_kernel<<<2048, 256, 0, stream>>>(row, cursor, E);
    scan1_kernel<<<nb, 256, 0, stream>>>(cursor, offs, bsums, n);
    scan2_kernel<<<1, 256, 0, stream>>>(bsums, nb);
    scan3_kernel<<<nb, 256, 0, stream>>>(offs, cursor, bsums, bcur, n, E);
    scatterA<<<(E + 2047) / 2048, 256, 0, stream>>>(row, col, val, bcur, tmpE, E, nbk);
    scatterB<<<nbk, 256, 0, stream>>>(tmpE, offs, cursor, cvA, n);

    const int gB = (n + 63) / 64;       // gemmF row tiles (782)

    // Layer 1 (multiply-first): s1 = x[:,:128] @ W1 (linear) -> hB; h1 = relu(agg(s1)+b1) -> hA
    gemmF<128, 96, false, false, true><<<gB, 256, 0, stream>>>(x, XLD, 128, x, XLD,
        W1, b1, nullptr, nullptr, hB, bsum, bsumsq, n);
    aggB<<<GA, 256, 0, stream>>>(hB, offs, cvA, b1, hA, vsum, pbuf, n);
    bn_reduce<<<64, 256, 0, stream>>>(pbuf, stats, GA);

    // Layers 2-4: split gather + GEMM, ping-pong
    fold_kernel<96><<<1, 256, 0, stream>>>(W2, bsum, bsumsq, Wf, cb, n);
    aggP<3, false><<<GA, 256, 0, stream>>>(hA, 96, offs, cvA, hB, nullptr, n);
    gemmF<96, 96, true, true><<<gB, 256, 0, stream>>>(hB, 96, 96, hB, 96,
        Wf, b2, cb, vsum, hA, bsum, bsumsq, n);

    fold_kernel<96><<<1, 256, 0, stream>>>(W3, bsum, bsumsq, Wf, cb, n);
    aggP<3, false><<<GA, 256, 0, stream>>>(hA, 96, offs, cvA, hB, nullptr, n);
    gemmF<96, 96, true, true><<<gB, 256, 0, stream>>>(hB, 96, 96, hB, 96,
        Wf, b3, cb, vsum, hA, bsum, bsumsq, n);

    fold_kernel<96><<<1, 256, 0, stream>>>(W4, bsum, bsumsq, Wf, cb, n);
    aggP<3, false><<<GA, 256, 0, stream>>>(hA, 96, offs, cvA, hB, nullptr, n);
    gemmF<96, 96, true, true><<<gB, 256, 0, stream>>>(hB, 96, 96, hB, 96,
        Wf, b4, cb, vsum, hA, bsum, bsumsq, n);

    // Layer 5 (multiply-first): s5 = h4 @ W5f (linear, n x 64) -> hB; h5 = relu(agg(s5)+vsum*cb+b5) -> hA
    fold_kernel<64><<<1, 256, 0, stream>>>(W5, bsum, bsumsq, Wf, cb, n);
    gemmF<96, 64, false, false, true><<<gB, 256, 0, stream>>>(hA, 96, 96, hA, 96,
        Wf, b5, nullptr, nullptr, hB, bsum, bsumsq, n);
    aggC<<<GA, 256, 0, stream>>>(hB, offs, cvA, b5, cb, vsum, hA, n);

    // MLP
    gemmF<96, 128, false, false><<<gB, 256, 0, stream>>>(hA, 64, 64, x + 128, XLD,
        M1w, M1b, nullptr, nullptr, hB, bsum, bsumsq, n);
    gemmF<128, 64, false, false, false, true><<<gB, 256, 0, stream>>>(hB, 128, 128, hB, 128,
        M2w, M2b, M3w, M3b, m, (float*)gmin, nullptr, n);

    // where(grp==0, min, m) fused with level-0 select histogram
    where_hist<<<64, 256, 0, stream>>>(x, m, gmin, h0, n);

    // exact 71st-largest threshold (two-level LDS radix)
    sel_pick8<<<1, 256, 0, stream>>>(h0, nullptr, 71, &pick[0], &pick[1]);
    sel_hist8b<<<64, 256, 0, stream>>>(m, pick, h1, n);
    sel_pick8<<<1, 256, 0, stream>>>(h1, &pick[1], 0, &pick[2], &pick[3]);
    sel_collect<<<64, 256, 0, stream>>>(m, pick, sbuf, scnt, n);
    sel_final<<<1, 1024, 0, stream>>>(sbuf, scnt, pick, thresh);

    // out = m>thresh ? m*(1/m) : 0
    mask_kernel<<<(n + 255) / 256, 256, 0, stream>>>(m, thresh, (float*)d_out, n);
}